// Round 5
// baseline (92.001 us; speedup 1.0000x reference)
//
#include <hip/hip_runtime.h>
#include <math.h>

// Problem geometry
#define MTOT  16384      // B*L
#define DM    1024
#define HIDN  128
#define HNB   256
#define NBAT  4
#define CL    32         // rows per k_mega block == scan chunk
#define NCH   128        // chunks per sequence
#define NBLK  512        // total chunks / k_mega blocks

typedef _Float16 v8h __attribute__((ext_vector_type(8)));
typedef float    v4f __attribute__((ext_vector_type(4)));
#define MFMA16(a,b,c) __builtin_amdgcn_mfma_f32_16x16x32_f16((a),(b),(c),0,0,0)

// Weight blobs (in out1 region; overwritten by k_apply_fill at the end):
//  [0,655360):      W1 k-tiles kt=0..31, 20480 B: {W1h[col=128][40 fp16] | W1l}
//  [655360,819200): W2 k-tiles ks=0..3, 40960 B: {W2h[col=256][40] | W2l}
// rows are 80 B (32 k + 8 pad fp16) -> per-lane 16 B fragment reads.
#define W1BLOB_TILE 20480
#define W2BLOB_BASE 655360
#define W2BLOB_TILE 40960

// ---------------------------------------------------------------------------
// K0: convert+transpose+pad weights into fp16 split blobs (same as R4).
//     Xh = fp16(x); Xl = fp16((x - Xh) * 4096)
// ---------------------------------------------------------------------------
__global__ __launch_bounds__(256) void k_prep(
    const float* __restrict__ W1,   // [1024][128]
    const float* __restrict__ W2,   // [128][256]
    char* __restrict__ blobs)
{
    __shared__ float lds[32][260];
    const int t = threadIdx.x, blk = blockIdx.x;
    if (blk < 32) {
        const int k0 = blk * 32;
        #pragma unroll
        for (int i = 0; i < 4; ++i) {
            int j = t + i * 256;
            int k = j >> 5, n4 = (j & 31) << 2;
            *(float4*)&lds[k][n4] = *(const float4*)&W1[(size_t)(k0 + k) * HIDN + n4];
        }
        __syncthreads();
        const int n = t >> 1, kh = t & 1;
        union { _Float16 h[16]; int2 v[4]; } uh, ul;
        #pragma unroll
        for (int kk = 0; kk < 16; ++kk) {
            float v = lds[kh * 16 + kk][n];
            _Float16 hh = (_Float16)v;
            uh.h[kk] = hh;
            ul.h[kk] = (_Float16)((v - (float)hh) * 4096.f);
        }
        char* bh = blobs + blk * W1BLOB_TILE + n * 80 + kh * 32;
        #pragma unroll
        for (int i = 0; i < 4; ++i) {
            *(int2*)(bh + i * 8)         = uh.v[i];
            *(int2*)(bh + 10240 + i * 8) = ul.v[i];
        }
        if (kh == 1) {
            int2 z; z.x = 0; z.y = 0;
            char* ph = blobs + blk * W1BLOB_TILE + n * 80 + 64;
            *(int2*)(ph) = z; *(int2*)(ph + 8) = z;
            *(int2*)(ph + 10240) = z; *(int2*)(ph + 10240 + 8) = z;
        }
    } else {
        const int ks = blk - 32, k0 = ks * 32;
        #pragma unroll
        for (int i = 0; i < 8; ++i) {
            int j = t + i * 256;
            int k = j >> 6, n4 = (j & 63) << 2;
            *(float4*)&lds[k][n4] = *(const float4*)&W2[(size_t)(k0 + k) * HNB + n4];
        }
        __syncthreads();
        const int n = t;
        union { _Float16 h[40]; int2 v[10]; } uh, ul;
        #pragma unroll
        for (int kk = 0; kk < 32; ++kk) {
            float v = lds[kk][n];
            _Float16 hh = (_Float16)v;
            uh.h[kk] = hh;
            ul.h[kk] = (_Float16)((v - (float)hh) * 4096.f);
        }
        #pragma unroll
        for (int kk = 32; kk < 40; ++kk) { uh.h[kk] = (_Float16)0.f; ul.h[kk] = (_Float16)0.f; }
        char* bh = blobs + W2BLOB_BASE + ks * W2BLOB_TILE + n * 80;
        #pragma unroll
        for (int i = 0; i < 10; ++i) {
            *(int2*)(bh + i * 8)         = uh.v[i];
            *(int2*)(bh + 20480 + i * 8) = ul.v[i];
        }
    }
}

// ---------------------------------------------------------------------------
// K1: mega. One block = 32 rows = one scan chunk. 512 threads, grid 512.
//   GEMM1: zero-LDS, zero-barrier — A per-lane direct fp32 loads (+reg split),
//          W1 per-lane fragment loads from L2 blob.
//   GELU -> H split via 17 KB LDS (1 barrier) -> GEMM2 (W2 per-lane from L2)
//   -> u -> LDS transpose -> in-block scan -> S=theta+d_loc, K-fill, carry.
// ---------------------------------------------------------------------------
__global__ __launch_bounds__(512, 4) void k_mega(
    const float* __restrict__ A,      // content [16384][1024]
    const float* __restrict__ theta,  // [16384][256]
    const float* __restrict__ b1, const float* __restrict__ b2,
    const float* __restrict__ logPi, const float* __restrict__ logR,
    const char* __restrict__ blobs,
    float* __restrict__ out0,         // S
    float* __restrict__ out2,         // K fill
    float* __restrict__ carry)        // out3: slot blk*8192 + c
{
    __shared__ __attribute__((aligned(16))) char smem[33280];
    // phase A: Hh @0 (8704 B), Hl @8704 (8704 B)
    // phase B: u[32][260] fp32 @0 (33280 B)

    const int tid  = threadIdx.x;
    const int blk  = blockIdx.x;
    const int m0   = blk * CL;
    const int lane = tid & 63;
    const int wid  = tid >> 6;
    const int ln15 = lane & 15;
    const int q    = lane >> 4;
    const int mp   = wid & 1;    // row half: 16*mp..+16
    const int np   = wid >> 1;   // 0..3

    // ---------------- GEMM1: out 32x128, K=1024 ----------------
    const float* arow = A + (size_t)(m0 + 16 * mp + ln15) * DM + q * 8;
    const char*  w1p  = blobs + (32 * np + ln15) * 80 + q * 16;

    v4f acc1[2], acc2[2];
    acc1[0] = acc1[1] = (v4f){0.f, 0.f, 0.f, 0.f};
    acc2[0] = acc2[1] = (v4f){0.f, 0.f, 0.f, 0.f};

    float4 a0 = *(const float4*)(arow);
    float4 a1 = *(const float4*)(arow + 4);
    v8h wh0 = *(const v8h*)(w1p);
    v8h wh1 = *(const v8h*)(w1p + 1280);
    v8h wl0 = *(const v8h*)(w1p + 10240);
    v8h wl1 = *(const v8h*)(w1p + 11520);

    for (int kt = 0; kt < 32; ++kt) {
        const int ktn = (kt < 31) ? (kt + 1) : 31;
        const float* ap = arow + ktn * 32;
        float4 na0 = *(const float4*)(ap);
        float4 na1 = *(const float4*)(ap + 4);
        const char* wp = w1p + ktn * W1BLOB_TILE;
        v8h nh0 = *(const v8h*)(wp);
        v8h nh1 = *(const v8h*)(wp + 1280);
        v8h nl0 = *(const v8h*)(wp + 10240);
        v8h nl1 = *(const v8h*)(wp + 11520);

        float av[8] = {a0.x, a0.y, a0.z, a0.w, a1.x, a1.y, a1.z, a1.w};
        v8h ah, al;
        #pragma unroll
        for (int e = 0; e < 8; ++e) {
            _Float16 hh = (_Float16)av[e];
            ah[e] = hh;
            al[e] = (_Float16)((av[e] - (float)hh) * 4096.f);
        }
        acc1[0] = MFMA16(ah, wh0, acc1[0]);
        acc1[1] = MFMA16(ah, wh1, acc1[1]);
        acc2[0] = MFMA16(ah, wl0, acc2[0]);
        acc2[0] = MFMA16(al, wh0, acc2[0]);
        acc2[1] = MFMA16(ah, wl1, acc2[1]);
        acc2[1] = MFMA16(al, wh1, acc2[1]);

        a0 = na0; a1 = na1;
        wh0 = nh0; wh1 = nh1; wl0 = nl0; wl1 = nl1;
    }

    // ---------------- GELU -> H split into LDS ----------------
    #pragma unroll
    for (int ni = 0; ni < 2; ++ni) {
        const int col = 32 * np + 16 * ni + ln15;
        const float bv = b1[col];
        #pragma unroll
        for (int r = 0; r < 4; ++r) {
            float y = acc1[ni][r] + acc2[ni][r] * (1.f / 4096.f) + bv;
            float h = 0.5f * y * (1.f + erff(y * 0.70710678118654752f));
            _Float16 hh = (_Float16)h;
            _Float16 hl = (_Float16)((h - (float)hh) * 4096.f);
            const int row = 16 * mp + 4 * q + r;
            *(_Float16*)(smem + row * 272 + col * 2)        = hh;
            *(_Float16*)(smem + 8704 + row * 272 + col * 2) = hl;
        }
    }
    __syncthreads();

    // ---------------- GEMM2: out 32x256, K=128 ----------------
    v4f c1[4], c2[4];
    #pragma unroll
    for (int i = 0; i < 4; ++i) {
        c1[i] = (v4f){0.f, 0.f, 0.f, 0.f};
        c2[i] = (v4f){0.f, 0.f, 0.f, 0.f};
    }
    const char* hbase = smem + (16 * mp + ln15) * 272 + q * 16;
    const char* w2p   = blobs + W2BLOB_BASE + (64 * np + ln15) * 80 + q * 16;

    #pragma unroll
    for (int ks = 0; ks < 4; ++ks) {
        v8h hh = *(const v8h*)(hbase + ks * 64);
        v8h hl = *(const v8h*)(hbase + 8704 + ks * 64);
        #pragma unroll
        for (int ni = 0; ni < 4; ++ni) {
            const char* wp = w2p + ks * W2BLOB_TILE + ni * 1280;
            v8h w2h = *(const v8h*)(wp);
            v8h w2l = *(const v8h*)(wp + 20480);
            c1[ni] = MFMA16(hh, w2h, c1[ni]);
            c2[ni] = MFMA16(hh, w2l, c2[ni]);
            c2[ni] = MFMA16(hl, w2h, c2[ni]);
        }
    }
    __syncthreads();   // H dead; smem becomes u[32][260]

    // ---------------- u-transform -> LDS (transposable layout) ----------------
    #pragma unroll
    for (int ni = 0; ni < 4; ++ni) {
        const int col = 64 * np + 16 * ni + ln15;
        const float Pi = expf(logPi[col]);
        const float Rr = expf(logR[col]);
        const float Kv = Pi / fmaxf(Pi + Rr, 1e-8f);
        const float bv = b2[col];
        #pragma unroll
        for (int r = 0; r < 4; ++r) {
            const int row = 16 * mp + 4 * q + r;
            float y2 = c1[ni][r] + c2[ni][r] * (1.f / 4096.f) + bv;
            float z  = 3.14159265358979323846f * tanhf(y2);
            float th = theta[(size_t)(m0 + row) * HNB + col];
            float diff = z - th;
            float kq = rintf(diff * 0.15915494309189533577f);
            float nu = (float)((double)diff - (double)kq * 6.283185307179586476925286766559);
            *(float*)(smem + row * 1040 + col * 4) = Kv * nu;
        }
    }
    __syncthreads();

    // ---------------- in-block scan; S, K-fill, carry ----------------
    if (tid < 256) {
        const int c = tid;
        const float Pi = expf(logPi[c]);
        const float Rr = expf(logR[c]);
        const float Kc = Pi / fmaxf(Pi + Rr, 1e-8f);
        const float alpha = 1.f - Kc;
        float d = 0.f;
        #pragma unroll
        for (int g = 0; g < 4; ++g) {
            float tv[8];
            #pragma unroll
            for (int j = 0; j < 8; ++j)
                tv[j] = theta[(size_t)(m0 + g * 8 + j) * HNB + c];
            #pragma unroll
            for (int j = 0; j < 8; ++j) {
                d = fmaf(alpha, d, *(const float*)(smem + (g * 8 + j) * 1040 + c * 4));
                tv[j] += d;
            }
            #pragma unroll
            for (int j = 0; j < 8; ++j) {
                size_t idx = (size_t)(m0 + g * 8 + j) * HNB + c;
                out0[idx] = tv[j];
                out2[idx] = Kc;
            }
        }
        carry[(size_t)blk * 8192 + c] = d;
    }
}

// ---------------------------------------------------------------------------
// K2: exclusive scan of chunk carries (factor alpha^32); incoming D replicated
//     into rows {0,16} of each chunk's slot for the two apply half-blocks.
// ---------------------------------------------------------------------------
__global__ __launch_bounds__(256) void k_cscan(
    const float* __restrict__ logPi,
    const float* __restrict__ logR,
    float* __restrict__ carry)
{
    const int c = threadIdx.x;
    const int b = blockIdx.x;
    const float Pi = expf(logPi[c]);
    const float Rr = expf(logR[c]);
    const float alpha = 1.f - Pi / fmaxf(Pi + Rr, 1e-8f);
    float A32 = alpha;
    #pragma unroll
    for (int i = 0; i < 5; ++i) A32 = A32 * A32;   // alpha^32
    float D = 0.f;
    for (int batch = 0; batch < NCH / 16; ++batch) {
        float a[16];
        #pragma unroll
        for (int j = 0; j < 16; ++j)
            a[j] = carry[(size_t)(b * NCH + batch * 16 + j) * 8192 + c];
        #pragma unroll
        for (int j = 0; j < 16; ++j) {
            size_t base = (size_t)(b * NCH + batch * 16 + j) * 8192;
            carry[base + c]        = D;
            carry[base + 4096 + c] = D;
            D = fmaf(A32, D, a[j]);
        }
    }
}

// ---------------------------------------------------------------------------
// K3: fills Pi (out1), R (out3); carry propagation into out0 with runtime
//     skip when the contribution is below fp32 significance (exact fallback).
//     grid 1024: block = (chunk, 16-row half). D read-before-fill in-slot.
// ---------------------------------------------------------------------------
__global__ __launch_bounds__(256) void k_apply_fill(
    const float* __restrict__ logPi,
    const float* __restrict__ logR,
    float* __restrict__ out0, float* __restrict__ out1,
    float* __restrict__ out3)
{
    const int blk = blockIdx.x;
    const int g = blk >> 1, half = blk & 1;
    const int c = threadIdx.x;
    const float Pi = expf(logPi[c]);
    const float Rr = expf(logR[c]);
    const float Kc = Pi / fmaxf(Pi + Rr, 1e-8f);
    const float alpha = 1.f - Kc;
    const size_t base = (size_t)g * 8192 + (size_t)half * 4096 + c;
    float D = out3[base];
    float w = (half == 0) ? alpha * D
                          : D * exp2f(__log2f(alpha) * 17.f);
    const bool skip = __all(fabsf(w) < 1e-25f) != 0;
    #pragma unroll 4
    for (int i = 0; i < 16; ++i) {
        size_t idx = base + (size_t)i * 256;
        out1[idx] = Pi;
        out3[idx] = Rr;
        if (!skip) { out0[idx] += w; w *= alpha; }
    }
}

extern "C" void kernel_launch(void* const* d_in, const int* in_sizes, int n_in,
                              void* d_out, int out_size, void* d_ws, size_t ws_size,
                              hipStream_t stream) {
    const float* theta   = (const float*)d_in[0];
    const float* content = (const float*)d_in[1];
    const float* W1      = (const float*)d_in[2];
    const float* b1      = (const float*)d_in[3];
    const float* W2      = (const float*)d_in[4];
    const float* b2      = (const float*)d_in[5];
    const float* logPi   = (const float*)d_in[6];
    const float* logR    = (const float*)d_in[7];

    float* out  = (float*)d_out;
    float* out0 = out;
    float* out1 = out + (size_t)MTOT * HNB;
    float* out2 = out + (size_t)2 * MTOT * HNB;
    float* out3 = out + (size_t)3 * MTOT * HNB;
    char*  blobs = (char*)out1;   // weight blobs until k_apply_fill fills out1

    hipLaunchKernelGGL(k_prep, dim3(36), dim3(256), 0, stream, W1, W2, blobs);
    hipLaunchKernelGGL(k_mega, dim3(NBLK), dim3(512), 0, stream,
                       content, theta, b1, b2, logPi, logR, blobs,
                       out0, out2, out3);
    hipLaunchKernelGGL(k_cscan, dim3(NBAT), dim3(256), 0, stream,
                       logPi, logR, out3);
    hipLaunchKernelGGL(k_apply_fill, dim3(NBLK * 2), dim3(256), 0, stream,
                       logPi, logR, out0, out1, out3);
}